// Round 13
// baseline (596.381 us; speedup 1.0000x reference)
//
#include <hip/hip_runtime.h>

// LSTMForecaster: B=4096, T=512, D=1, H=64, 2 layers + FC(64->1).
// R13: MERGED-ROLE free-running waves -- one poll, one publish, minimal LDS.
//   R12 analysis: per-wave serial step == whole measured step (MfmaUtil 34% at
//   3 waves/SIMD); two class-sync chains + duplicated h0 reads dominate idle.
//   Fix: 8 waves (512 thr, 2/SIMD); wave w owns units [8w,8w+8) of BOTH layers.
//   Step t computes L0(t) AND L1(t-1), both from old state {h0(t-1), h1(t-2)}:
//     xv -> poll min8(fl)>=t-1 -> read h0 (2 b128, shared by L0 and L1's Wih1
//     term) + h1 (2 b128) -> 8 L0-MFMA -> 16 L1-MFMA -> cell0 -> write h0(t)
//     -> cell1 -> write h1(t-1) -> lgkmcnt(0) -> publish fl[w]=t.
//   24 MFMA/wave (48/SIMD = 931 cyc wall unchanged), 2 cell2/wave, 4 b128/wave
//   (32/CU, lowest yet). Rings depth 4 (lockstep spread <=1 proven safe).
//   Math = R9/R10 (absmax 1.22e-4): 2-term W-split bf16 GEMM, single-bf16 h,
//   exp2-folded gate scales, packed cells.

#define TT 512
#define HH 64
#define NB 16
#define XP 516

typedef __bf16 bf16_t;
typedef bf16_t bf16x8 __attribute__((ext_vector_type(8)));
typedef float  f32x4  __attribute__((ext_vector_type(4)));
typedef float  f32x2  __attribute__((ext_vector_type(2)));

#define MFMA(A, B, C) __builtin_amdgcn_mfma_f32_16x16x32_bf16((A), (B), (C), 0, 0, 0)
#define RCPF(x) __builtin_amdgcn_rcpf(x)

#if __has_builtin(__builtin_amdgcn_exp2f)
#define EXP2F(x) __builtin_amdgcn_exp2f(x)
#else
__device__ __forceinline__ float EXP2F(float x) {
    float r;
    asm volatile("v_exp_f32 %0, %1" : "=v"(r) : "v"(x));
    return r;
}
#endif

#define SC_IFO (-1.4426950408889634f)   // -log2(e)
#define SC_G   ( 2.8853900817779268f)   // +2*log2(e)

__device__ __forceinline__ unsigned short f32_to_bf16_rne(float f) {
    unsigned int u = __builtin_bit_cast(unsigned int, f);
    unsigned int r = u + 0x7fffu + ((u >> 16) & 1u);
    return (unsigned short)(r >> 16);
}
__device__ __forceinline__ float bf16bits_to_f32(unsigned short s) {
    return __builtin_bit_cast(float, ((unsigned int)s) << 16);
}
__device__ __forceinline__ bf16_t bits_to_bf16(unsigned short u) {
    return __builtin_bit_cast(bf16_t, u);
}
__device__ __forceinline__ void build_frags_scaled(const float* __restrict__ p, float sc,
                                                   bf16x8& hi, bf16x8& lo) {
    const float4 a = *(const float4*)p;
    const float4 b = *(const float4*)(p + 4);
    float v[8] = {a.x, a.y, a.z, a.w, b.x, b.y, b.z, b.w};
#pragma unroll
    for (int jj = 0; jj < 8; ++jj) {
        const float s = v[jj] * sc;
        unsigned short h = f32_to_bf16_rne(s);
        float d = s - bf16bits_to_f32(h);
        hi[jj] = bits_to_bf16(h);
        lo[jj] = bits_to_bf16(f32_to_bf16_rne(d));
    }
}

__device__ __forceinline__ f32x2 exp2v(f32x2 v) {
    f32x2 r; r[0] = EXP2F(v[0]); r[1] = EXP2F(v[1]); return r;
}
__device__ __forceinline__ f32x2 rcpv(f32x2 v) {
    f32x2 r; r[0] = RCPF(v[0]); r[1] = RCPF(v[1]); return r;
}
// Two cells on PRE-SCALED gates (is,fs,os scaled -log2e; gs scaled +2log2e).
__device__ __forceinline__ f32x2 cell2(const f32x4 a0, const f32x4 a1, f32x2* c) {
    f32x2 is = {a0[0], a1[0]}, fs = {a0[1], a1[1]};
    f32x2 gs = {a0[2], a1[2]}, os = {a0[3], a1[3]};
    const f32x2 pf = exp2v(fs);
    const f32x2 fg = rcpv(1.0f + pf);
    const f32x2 pi = exp2v(is);
    const f32x2 e2 = exp2v(gs);
    const f32x2 z  = (e2 - 1.0f) * rcpv((1.0f + pi) * (1.0f + e2));
    *c = fg * (*c) + z;
    const f32x2 po  = exp2v(os);
    const f32x2 e2c = exp2v((*c) * SC_G);
    return (e2c - 1.0f) * rcpv((1.0f + po) * (1.0f + e2c));
}

__device__ __forceinline__ int imin2(int a, int b) { return a < b ? a : b; }
__device__ __forceinline__ int min8of(const int* f) {
    const int4 a = *(const int4*)f;
    const int4 b = *(const int4*)(f + 4);
    return imin2(imin2(imin2(a.x, a.y), imin2(a.z, a.w)),
                 imin2(imin2(b.x, b.y), imin2(b.z, b.w)));
}

__global__ __launch_bounds__(512, 2)
void lstm_mrg_kernel(const float* __restrict__ x,
                     const float* __restrict__ Wih0, const float* __restrict__ Whh0,
                     const float* __restrict__ bih0, const float* __restrict__ bhh0,
                     const float* __restrict__ Wih1, const float* __restrict__ Whh1,
                     const float* __restrict__ bih1, const float* __restrict__ bhh1,
                     const float* __restrict__ Wfc,  const float* __restrict__ bfc,
                     float* __restrict__ out)
{
    __shared__ float xbuf[NB][XP];                   // 33 KB
    __shared__ unsigned short h0r[4][NB][64];        // 8 KB ring, slot t&3
    __shared__ unsigned short h1r[4][NB][64];        // 8 KB ring, slot (t-1)&3
    __shared__ float h1fin[HH][NB + 1];              // 4.25 KB
    __shared__ __align__(16) int fl[8];              // wave progress flags

    const int tid  = threadIdx.x;
    const int wv   = tid >> 6;       // 0..7: owns units [8wv,8wv+8) of BOTH layers
    const int lane = tid & 63;
    const int m    = lane & 15;      // batch col (B/C frag) & A-frag row-in-tile
    const int q    = lane >> 4;      // C-frag unit_local; A/B k-quad
    const int m7   = m & 7;
    const int b0   = blockIdx.x * NB;

    // ---- stage x (coalesced float4) ----
    for (int i = tid; i < NB * TT / 4; i += 512) {
        const int b  = i >> 7;
        const int t4 = i & 127;
        *(float4*)&xbuf[b][t4 * 4] = *(const float4*)&x[(size_t)(b0 + b) * TT + t4 * 4];
    }
    // ---- zero rings (h(-1)/h(-2) served by zeroed slots) + flags ----
    for (int i = tid; i < 4 * NB * 64; i += 512) {
        (&h0r[0][0][0])[i] = 0;
        (&h1r[0][0][0])[i] = 0;
    }
    if (tid < 8) fl[tid] = -1;

    // ---- per-lane read offsets (shorts within one slot = 1024) ----
    int roff[2];
#pragma unroll
    for (int kt = 0; kt < 2; ++kt)
        roff[kt] = m * 64 + (((4 * kt + q) ^ m7) * 8);

    const int gate_m = m & 3;
    const float scA  = (gate_m == 2) ? SC_G : SC_IFO;
    unsigned short* const H0 = &h0r[0][0][0];
    unsigned short* const H1 = &h1r[0][0][0];

    // ---- A-fragments: 2 unit-major tiles per layer-matrix ----
    bf16x8 A0h[2][2], A0l[2][2];     // [tau][kt] Whh0        (eats h0(t-1))
    bf16x8 B1h[2][2], B1l[2][2];     // [tau][kt] Wih1        (eats h0(t-1))
    bf16x8 C1h[2][2], C1l[2][2];     // [tau][kt] Whh1        (eats h1(t-2))
    f32x4 bb0s[2], wx0s[2], bb1s[2];
    int woff[2], uu[2];
#pragma unroll
    for (int tau = 0; tau < 2; ++tau) {
        const int rowA = 64 * gate_m + 8 * wv + 4 * tau + (m >> 2);
#pragma unroll
        for (int kt = 0; kt < 2; ++kt) {
            build_frags_scaled(&Whh0[rowA * HH + kt * 32 + q * 8], scA,
                               A0h[tau][kt], A0l[tau][kt]);
            build_frags_scaled(&Wih1[rowA * HH + kt * 32 + q * 8], scA,
                               B1h[tau][kt], B1l[tau][kt]);
            build_frags_scaled(&Whh1[rowA * HH + kt * 32 + q * 8], scA,
                               C1h[tau][kt], C1l[tau][kt]);
        }
#pragma unroll
        for (int r = 0; r < 4; ++r) {
            const int row = 64 * r + 8 * wv + 4 * tau + q;
            const float sc = (r == 2) ? SC_G : SC_IFO;
            bb0s[tau][r] = (bih0[row] + bhh0[row]) * sc;
            wx0s[tau][r] = Wih0[row] * sc;
            bb1s[tau][r] = (bih1[row] + bhh1[row]) * sc;
        }
        const int u = 8 * wv + 4 * tau + q;
        uu[tau]   = u;
        woff[tau] = m * 64 + (((u >> 3) ^ m7) * 8) + (u & 7);
    }

    f32x2 c0 = {0.f, 0.f}, c1 = {0.f, 0.f};

    __syncthreads();     // the ONLY barrier before the epilogue

#pragma unroll 1
    for (int t = 0; t <= TT; ++t) {
        const float xv = xbuf[m][(t < TT) ? t : 0];

        // ---- single poll: all waves completed step t-1 ----
        while (min8of(fl) < t - 1) {
            asm volatile("" ::: "memory");
            __builtin_amdgcn_s_sleep(1);
        }
        asm volatile("" ::: "memory");

        // ---- all reads: h0(t-1) shared by L0(t) and L1(t-1); h1(t-2) ----
        const int rs0 = ((t - 1) & 3) * (NB * 64);
        const int rs1 = ((t - 2) & 3) * (NB * 64);
        bf16x8 h0[2], h1[2];
        h0[0] = *(const bf16x8*)(H0 + rs0 + roff[0]);
        h0[1] = *(const bf16x8*)(H0 + rs0 + roff[1]);
        h1[0] = *(const bf16x8*)(H1 + rs1 + roff[0]);
        h1[1] = *(const bf16x8*)(H1 + rs1 + roff[1]);

        // ---- L0(t) gates: 8 MFMA (2 tiles x split chains) ----
        f32x4 a0[2];
#pragma unroll
        for (int tau = 0; tau < 2; ++tau) {
            f32x4 p;
#pragma unroll
            for (int r = 0; r < 4; ++r)
                p[r] = __builtin_fmaf(xv, wx0s[tau][r], bb0s[tau][r]);
            f32x4 z = {0.f, 0.f, 0.f, 0.f};
            p = MFMA(A0h[tau][0], h0[0], p);
            p = MFMA(A0l[tau][0], h0[0], p);
            z = MFMA(A0h[tau][1], h0[1], z);
            z = MFMA(A0l[tau][1], h0[1], z);
            a0[tau] = p + z;
        }

        // ---- L1(t-1) gates: 16 MFMA (2 tiles x split p/s chains) ----
        f32x4 a1[2];
#pragma unroll
        for (int tau = 0; tau < 2; ++tau) {
            f32x4 p = bb1s[tau];
            f32x4 s = {0.f, 0.f, 0.f, 0.f};
            p = MFMA(B1h[tau][0], h0[0], p);       // Wih1 . h0(t-1)
            p = MFMA(B1l[tau][0], h0[0], p);
            p = MFMA(B1h[tau][1], h0[1], p);
            p = MFMA(B1l[tau][1], h0[1], p);
            s = MFMA(C1h[tau][0], h1[0], s);       // Whh1 . h1(t-2)
            s = MFMA(C1l[tau][0], h1[0], s);
            s = MFMA(C1h[tau][1], h1[1], s);
            s = MFMA(C1l[tau][1], h1[1], s);
            a1[tau] = p + s;
        }

        // ---- L0 cell + write h0(t) (VALU drains while L1 MFMAs finish) ----
        const f32x2 hv0 = cell2(a0[0], a0[1], &c0);
        const int ws0 = (t & 3) * (NB * 64);
        H0[ws0 + woff[0]] = f32_to_bf16_rne(hv0[0]);
        H0[ws0 + woff[1]] = f32_to_bf16_rne(hv0[1]);

        // ---- L1 cell + write h1(t-1) ----
        f32x2 hv1 = cell2(a1[0], a1[1], &c1);
        if (t == 0) {                        // h1(-1) = 0; c1 stays 0
            hv1[0] = 0.f; hv1[1] = 0.f;
            c1[0] = 0.f;  c1[1] = 0.f;
        }
        if (t == TT) {                       // exact fp32 h1(T-1) for FC
            h1fin[uu[0]][m] = hv1[0];
            h1fin[uu[1]][m] = hv1[1];
        }
        const int ws1 = ((t - 1) & 3) * (NB * 64);
        H1[ws1 + woff[0]] = f32_to_bf16_rne(hv1[0]);
        H1[ws1 + woff[1]] = f32_to_bf16_rne(hv1[1]);

        // ---- publish ----
        asm volatile("s_waitcnt lgkmcnt(0)" ::: "memory");
        if (lane == 0) *(volatile int*)&fl[wv] = t;
    }

    __syncthreads();

    // ---- FC epilogue: out[b] = h1(T-1)[b] . Wfc + bfc ----
    if (tid < NB) {
        float sacc = bfc[0];
#pragma unroll
        for (int u = 0; u < HH; ++u) sacc = fmaf(h1fin[u][tid], Wfc[u], sacc);
        out[b0 + tid] = sacc;
    }
}

extern "C" void kernel_launch(void* const* d_in, const int* in_sizes, int n_in,
                              void* d_out, int out_size, void* d_ws, size_t ws_size,
                              hipStream_t stream) {
    const float* x    = (const float*)d_in[0];
    const float* Wih0 = (const float*)d_in[1];
    const float* Whh0 = (const float*)d_in[2];
    const float* bih0 = (const float*)d_in[3];
    const float* bhh0 = (const float*)d_in[4];
    const float* Wih1 = (const float*)d_in[5];
    const float* Whh1 = (const float*)d_in[6];
    const float* bih1 = (const float*)d_in[7];
    const float* bhh1 = (const float*)d_in[8];
    const float* Wfc  = (const float*)d_in[9];
    const float* bfc  = (const float*)d_in[10];

    lstm_mrg_kernel<<<dim3(4096 / NB), dim3(512), 0, stream>>>(
        x, Wih0, Whh0, bih0, bhh0, Wih1, Whh1, bih1, bhh1, Wfc, bfc, (float*)d_out);
}

// Round 14
// 556.376 us; speedup vs baseline: 1.0719x; 1.0719x over previous
//
#include <hip/hip_runtime.h>

// LSTMForecaster: B=4096, T=512, D=1, H=64, 2 layers + FC(64->1).
// R15 = R10 (best, 519us) + wave priority for the serial backbone.
//   Config sweep done: {2,3,4} waves/SIMD -> {596, 519, 639}; R10 optimal.
//   Model: step = MFMA wall + VALU wall + ~900 serial residue; h0 chain
//   (read->L0 MFMA->cell0->write->publish->detect) is the backbone (~800 cyc
//   natural latency) but gets stretched ~3x by round-robin issue contention
//   with co-resident L1 waves' bulk bursts.
//   Change 1: s_setprio 3 on L0 waves / 0 on L1 waves -- backbone wins SIMD
//   arbitration; L1's 32 MFMA/SIMD fill slack instead of blocking the chain.
//   Change 2: xv prefetched one step ahead (removes 120-cyc LDS read from the
//   post-poll critical path).
//   Everything else byte-identical to R10: 12 waves (4 L0 x 16u, 8 L1 x 8u),
//   h0 ring 8 / h1 ring 2, monotone flags, 2-term W-split bf16 GEMM,
//   single-bf16 h, exp2-folded scales, packed cells. absmax 1.22e-4.

#define TT 512
#define HH 64
#define NB 16
#define XP 516

typedef __bf16 bf16_t;
typedef bf16_t bf16x8 __attribute__((ext_vector_type(8)));
typedef float  f32x4  __attribute__((ext_vector_type(4)));
typedef float  f32x2  __attribute__((ext_vector_type(2)));

#define MFMA(A, B, C) __builtin_amdgcn_mfma_f32_16x16x32_bf16((A), (B), (C), 0, 0, 0)
#define RCPF(x) __builtin_amdgcn_rcpf(x)

#if __has_builtin(__builtin_amdgcn_exp2f)
#define EXP2F(x) __builtin_amdgcn_exp2f(x)
#else
__device__ __forceinline__ float EXP2F(float x) {
    float r;
    asm volatile("v_exp_f32 %0, %1" : "=v"(r) : "v"(x));
    return r;
}
#endif

#define SC_IFO (-1.4426950408889634f)   // -log2(e)
#define SC_G   ( 2.8853900817779268f)   // +2*log2(e)

__device__ __forceinline__ unsigned short f32_to_bf16_rne(float f) {
    unsigned int u = __builtin_bit_cast(unsigned int, f);
    unsigned int r = u + 0x7fffu + ((u >> 16) & 1u);
    return (unsigned short)(r >> 16);
}
__device__ __forceinline__ float bf16bits_to_f32(unsigned short s) {
    return __builtin_bit_cast(float, ((unsigned int)s) << 16);
}
__device__ __forceinline__ bf16_t bits_to_bf16(unsigned short u) {
    return __builtin_bit_cast(bf16_t, u);
}
__device__ __forceinline__ void build_frags_scaled(const float* __restrict__ p, float sc,
                                                   bf16x8& hi, bf16x8& lo) {
    const float4 a = *(const float4*)p;
    const float4 b = *(const float4*)(p + 4);
    float v[8] = {a.x, a.y, a.z, a.w, b.x, b.y, b.z, b.w};
#pragma unroll
    for (int jj = 0; jj < 8; ++jj) {
        const float s = v[jj] * sc;
        unsigned short h = f32_to_bf16_rne(s);
        float d = s - bf16bits_to_f32(h);
        hi[jj] = bits_to_bf16(h);
        lo[jj] = bits_to_bf16(f32_to_bf16_rne(d));
    }
}

__device__ __forceinline__ f32x2 exp2v(f32x2 v) {
    f32x2 r; r[0] = EXP2F(v[0]); r[1] = EXP2F(v[1]); return r;
}
__device__ __forceinline__ f32x2 rcpv(f32x2 v) {
    f32x2 r; r[0] = RCPF(v[0]); r[1] = RCPF(v[1]); return r;
}
// Two cells on PRE-SCALED gates (is,fs,os scaled -log2e; gs scaled +2log2e).
__device__ __forceinline__ f32x2 cell2(const f32x4 a0, const f32x4 a1, f32x2* c) {
    f32x2 is = {a0[0], a1[0]}, fs = {a0[1], a1[1]};
    f32x2 gs = {a0[2], a1[2]}, os = {a0[3], a1[3]};
    const f32x2 pf = exp2v(fs);
    const f32x2 fg = rcpv(1.0f + pf);
    const f32x2 pi = exp2v(is);
    const f32x2 e2 = exp2v(gs);
    const f32x2 z  = (e2 - 1.0f) * rcpv((1.0f + pi) * (1.0f + e2));
    *c = fg * (*c) + z;
    const f32x2 po  = exp2v(os);
    const f32x2 e2c = exp2v((*c) * SC_G);
    return (e2c - 1.0f) * rcpv((1.0f + po) * (1.0f + e2c));
}

__device__ __forceinline__ int imin2(int a, int b) { return a < b ? a : b; }
__device__ __forceinline__ int min4of(const int* f) {
    const int4 v = *(const int4*)f;
    return imin2(imin2(v.x, v.y), imin2(v.z, v.w));
}
__device__ __forceinline__ int min8of(const int* f) {
    const int4 a = *(const int4*)f;
    const int4 b = *(const int4*)(f + 4);
    return imin2(imin2(imin2(a.x, a.y), imin2(a.z, a.w)),
                 imin2(imin2(b.x, b.y), imin2(b.z, b.w)));
}

__global__ __launch_bounds__(768, 3)
void lstm_prio_kernel(const float* __restrict__ x,
                      const float* __restrict__ Wih0, const float* __restrict__ Whh0,
                      const float* __restrict__ bih0, const float* __restrict__ bhh0,
                      const float* __restrict__ Wih1, const float* __restrict__ Whh1,
                      const float* __restrict__ bih1, const float* __restrict__ bhh1,
                      const float* __restrict__ Wfc,  const float* __restrict__ bfc,
                      float* __restrict__ out)
{
    __shared__ float xbuf[NB][XP];                   // 33 KB
    __shared__ unsigned short h0r[8][NB][64];        // 16 KB ring, slot t&7
    __shared__ unsigned short h1r[2][NB][64];        // 4 KB ring, slot t&1
    __shared__ float h1fin[HH][NB + 1];              // 4.25 KB
    __shared__ __align__(16) int f0[4];              // L0 wave progress flags
    __shared__ __align__(16) int f1[8];              // L1 wave progress flags

    const int tid  = threadIdx.x;
    const int wv   = tid >> 6;       // 0..11: 0-3 L0 waves, 4-11 L1 waves
    const int lane = tid & 63;
    const int m    = lane & 15;      // batch col (B/C frag) & A-frag row-in-tile
    const int q    = lane >> 4;      // C-frag unit_local; A/B k-quad
    const int m7   = m & 7;
    const int b0   = blockIdx.x * NB;
    const bool isL0 = (wv < 4);

    // ---- stage x (coalesced float4) ----
    for (int i = tid; i < NB * TT / 4; i += 768) {
        const int b  = i >> 7;
        const int t4 = i & 127;
        *(float4*)&xbuf[b][t4 * 4] = *(const float4*)&x[(size_t)(b0 + b) * TT + t4 * 4];
    }
    // ---- zero rings (h(-1) served by zeroed slots) + flags ----
    for (int i = tid; i < 8 * NB * 64; i += 768) (&h0r[0][0][0])[i] = 0;
    for (int i = tid; i < 2 * NB * 64; i += 768) (&h1r[0][0][0])[i] = 0;
    if (tid < 4) f0[tid] = -1;
    else if (tid < 12) f1[tid - 4] = -1;

    // ---- per-lane read offsets (shorts within one slot = 1024) ----
    int roff[2];
#pragma unroll
    for (int kt = 0; kt < 2; ++kt)
        roff[kt] = m * 64 + (((4 * kt + q) ^ m7) * 8);

    const int gate_m = m & 3;
    const float scA  = (gate_m == 2) ? SC_G : SC_IFO;
    unsigned short* const H0 = &h0r[0][0][0];
    unsigned short* const H1 = &h1r[0][0][0];

    __syncthreads();     // the ONLY barrier before the epilogue

    if (isL0) {
        // ===== L0 waves (BACKBONE, prio 3): units [16w,16w+16), 16 MFMA =====
        asm volatile("s_setprio 3" ::: "memory");
        const int w = wv;
        bf16x8 Ah[4][2], Al[4][2];          // [tau][kt] of Whh0
        f32x4 bb0s[4], wx0s[4];
        int woff[4];
#pragma unroll
        for (int tau = 0; tau < 4; ++tau) {
            const int rowA = 64 * gate_m + 16 * w + 4 * tau + (m >> 2);
#pragma unroll
            for (int kt = 0; kt < 2; ++kt)
                build_frags_scaled(&Whh0[rowA * HH + kt * 32 + q * 8], scA,
                                   Ah[tau][kt], Al[tau][kt]);
#pragma unroll
            for (int r = 0; r < 4; ++r) {
                const int row = 64 * r + 16 * w + 4 * tau + q;
                const float sc = (r == 2) ? SC_G : SC_IFO;
                bb0s[tau][r] = (bih0[row] + bhh0[row]) * sc;
                wx0s[tau][r] = Wih0[row] * sc;
            }
            const int u = 16 * w + 4 * tau + q;
            woff[tau] = m * 64 + (((u >> 3) ^ m7) * 8) + (u & 7);
        }

        f32x2 cA = {0.f, 0.f}, cB = {0.f, 0.f};
        float xv = xbuf[m][0];              // prefetched

#pragma unroll 1
        for (int t = 0; t < TT; ++t) {
            const float xv_next = xbuf[m][(t + 1 < TT) ? (t + 1) : 0];

            // ---- wait for h0(t-1) complete (all 4 L0 waves) ----
            while (min4of(f0) < t - 1) {
                asm volatile("" ::: "memory");
                __builtin_amdgcn_s_sleep(1);
            }
            asm volatile("" ::: "memory");

            const int rs = ((t - 1) & 7) * (NB * 64);
            bf16x8 h0[2];
            h0[0] = *(const bf16x8*)(H0 + rs + roff[0]);
            h0[1] = *(const bf16x8*)(H0 + rs + roff[1]);

            f32x4 a[4];
#pragma unroll
            for (int tau = 0; tau < 4; ++tau) {
                f32x4 p;
#pragma unroll
                for (int r = 0; r < 4; ++r)
                    p[r] = __builtin_fmaf(xv, wx0s[tau][r], bb0s[tau][r]);
                f32x4 z = {0.f, 0.f, 0.f, 0.f};
                p = MFMA(Ah[tau][0], h0[0], p);
                p = MFMA(Al[tau][0], h0[0], p);
                z = MFMA(Ah[tau][1], h0[1], z);
                z = MFMA(Al[tau][1], h0[1], z);
                a[tau] = p + z;
            }

            // ---- back-pressure: slot t&7 (h0(t-8)) fully consumed by L1 ----
            while (min8of(f1) < t - 8) {
                asm volatile("" ::: "memory");
                __builtin_amdgcn_s_sleep(1);
            }
            asm volatile("" ::: "memory");

            const f32x2 hv0 = cell2(a[0], a[1], &cA);
            const f32x2 hv1 = cell2(a[2], a[3], &cB);

            const int ws = (t & 7) * (NB * 64);
            H0[ws + woff[0]] = f32_to_bf16_rne(hv0[0]);
            H0[ws + woff[1]] = f32_to_bf16_rne(hv0[1]);
            H0[ws + woff[2]] = f32_to_bf16_rne(hv1[0]);
            H0[ws + woff[3]] = f32_to_bf16_rne(hv1[1]);

            asm volatile("s_waitcnt lgkmcnt(0)" ::: "memory");
            if (lane == 0) *(volatile int*)&f0[w] = t;
            xv = xv_next;
        }
        asm volatile("s_setprio 0" ::: "memory");
    } else {
        // ===== L1 waves (bulk, prio 0): units [8u,8u+8), 16 MFMA =====
        asm volatile("s_setprio 0" ::: "memory");
        const int uW = wv - 4;
        bf16x8 Ah[2][4], Al[2][4];   // [tau][kt]: kt0-1 Wih1 (eats h0), kt2-3 Whh1 (eats h1)
        f32x4 bb1s[2];
        int woff[2], uu[2];
#pragma unroll
        for (int tau = 0; tau < 2; ++tau) {
            const int rowA = 64 * gate_m + 8 * uW + 4 * tau + (m >> 2);
#pragma unroll
            for (int kt = 0; kt < 2; ++kt)
                build_frags_scaled(&Wih1[rowA * HH + kt * 32 + q * 8], scA,
                                   Ah[tau][kt], Al[tau][kt]);
#pragma unroll
            for (int kt = 0; kt < 2; ++kt)
                build_frags_scaled(&Whh1[rowA * HH + kt * 32 + q * 8], scA,
                                   Ah[tau][2 + kt], Al[tau][2 + kt]);
#pragma unroll
            for (int r = 0; r < 4; ++r) {
                const int row = 64 * r + 8 * uW + 4 * tau + q;
                const float sc = (r == 2) ? SC_G : SC_IFO;
                bb1s[tau][r] = (bih1[row] + bhh1[row]) * sc;
            }
            const int u = 8 * uW + 4 * tau + q;
            uu[tau]   = u;
            woff[tau] = m * 64 + (((u >> 3) ^ m7) * 8) + (u & 7);
        }

        f32x2 c1 = {0.f, 0.f};

#pragma unroll 1
        for (int t = 0; t < TT; ++t) {
            // ---- wait for h0(t) (all 4 L0 waves) ----
            while (min4of(f0) < t) {
                asm volatile("" ::: "memory");
                __builtin_amdgcn_s_sleep(1);
            }
            asm volatile("" ::: "memory");
            const int rs0 = (t & 7) * (NB * 64);
            bf16x8 h0[2];
            h0[0] = *(const bf16x8*)(H0 + rs0 + roff[0]);
            h0[1] = *(const bf16x8*)(H0 + rs0 + roff[1]);

            // ---- wait for h1(t-1) (all 8 L1 waves) ----
            while (min8of(f1) < t - 1) {
                asm volatile("" ::: "memory");
                __builtin_amdgcn_s_sleep(1);
            }
            asm volatile("" ::: "memory");
            const int rs1 = ((t - 1) & 1) * (NB * 64);
            bf16x8 h1[2];
            h1[0] = *(const bf16x8*)(H1 + rs1 + roff[0]);
            h1[1] = *(const bf16x8*)(H1 + rs1 + roff[1]);

            f32x4 a[2];
#pragma unroll
            for (int tau = 0; tau < 2; ++tau) {
                f32x4 p = bb1s[tau];
                f32x4 s = {0.f, 0.f, 0.f, 0.f};
                p = MFMA(Ah[tau][0], h0[0], p);        // Wih1 . h0(t)
                p = MFMA(Al[tau][0], h0[0], p);
                p = MFMA(Ah[tau][1], h0[1], p);
                p = MFMA(Al[tau][1], h0[1], p);
                s = MFMA(Ah[tau][2], h1[0], s);        // Whh1 . h1(t-1)
                s = MFMA(Al[tau][2], h1[0], s);
                s = MFMA(Ah[tau][3], h1[1], s);
                s = MFMA(Al[tau][3], h1[1], s);
                a[tau] = p + s;
            }

            const f32x2 hv = cell2(a[0], a[1], &c1);
            if (t == TT - 1) {                  // exact fp32 h1(T-1) for FC
                h1fin[uu[0]][m] = hv[0];
                h1fin[uu[1]][m] = hv[1];
            }
            const int ws = (t & 1) * (NB * 64);
            H1[ws + woff[0]] = f32_to_bf16_rne(hv[0]);
            H1[ws + woff[1]] = f32_to_bf16_rne(hv[1]);

            asm volatile("s_waitcnt lgkmcnt(0)" ::: "memory");
            if (lane == 0) *(volatile int*)&f1[uW] = t;
        }
    }

    __syncthreads();

    // ---- FC epilogue: out[b] = h1(T-1)[b] . Wfc + bfc ----
    if (tid < NB) {
        float sacc = bfc[0];
#pragma unroll
        for (int u = 0; u < HH; ++u) sacc = fmaf(h1fin[u][tid], Wfc[u], sacc);
        out[b0 + tid] = sacc;
    }
}

extern "C" void kernel_launch(void* const* d_in, const int* in_sizes, int n_in,
                              void* d_out, int out_size, void* d_ws, size_t ws_size,
                              hipStream_t stream) {
    const float* x    = (const float*)d_in[0];
    const float* Wih0 = (const float*)d_in[1];
    const float* Whh0 = (const float*)d_in[2];
    const float* bih0 = (const float*)d_in[3];
    const float* bhh0 = (const float*)d_in[4];
    const float* Wih1 = (const float*)d_in[5];
    const float* Whh1 = (const float*)d_in[6];
    const float* bih1 = (const float*)d_in[7];
    const float* bhh1 = (const float*)d_in[8];
    const float* Wfc  = (const float*)d_in[9];
    const float* bfc  = (const float*)d_in[10];

    lstm_prio_kernel<<<dim3(4096 / NB), dim3(768), 0, stream>>>(
        x, Wih0, Whh0, bih0, bhh0, Wih1, Whh1, bih1, bhh1, Wfc, bfc, (float*)d_out);
}

// Round 15
// 493.360 us; speedup vs baseline: 1.2088x; 1.1277x over previous
//
#include <hip/hip_runtime.h>

// LSTMForecaster: B=4096, T=512, D=1, H=64, 2 layers + FC(64->1).
// R16 = R10 champion structure + SINGLE-TERM bf16 weight GEMM (drop Wlo).
//   Scheduling knobs are exhausted (R11-R15 all 519-705us): step = MFMA issue
//   (851) + VALU (584) + ~1000 sticky stall. Only work-volume cuts have paid.
//   Change: weights stored as single RNE bf16 (no hi/lo split) -> MFMA count
//   halves 192->96/CU/step (24/SIMD, wall 466), chains halve, VGPR drops.
//   Error: h-quant (2^-10 RMS) gave 1.22e-4; W-quant adds an independent
//   2^-10 term -> predicted absmax ~1.7e-4 (tail 2.8e-4) < 3.784e-4 threshold.
//   If FAIL: revert to R10 (2-term, 519us).
//   Everything else byte-identical to R10: 12 waves (4 L0 x 16u, 8 L1 x 8u),
//   free-running flag sync, h0 ring 8 / h1 ring 2, single-bf16 h state,
//   exp2-folded gate scales, packed cells.

#define TT 512
#define HH 64
#define NB 16
#define XP 516

typedef __bf16 bf16_t;
typedef bf16_t bf16x8 __attribute__((ext_vector_type(8)));
typedef float  f32x4  __attribute__((ext_vector_type(4)));
typedef float  f32x2  __attribute__((ext_vector_type(2)));

#define MFMA(A, B, C) __builtin_amdgcn_mfma_f32_16x16x32_bf16((A), (B), (C), 0, 0, 0)
#define RCPF(x) __builtin_amdgcn_rcpf(x)

#if __has_builtin(__builtin_amdgcn_exp2f)
#define EXP2F(x) __builtin_amdgcn_exp2f(x)
#else
__device__ __forceinline__ float EXP2F(float x) {
    float r;
    asm volatile("v_exp_f32 %0, %1" : "=v"(r) : "v"(x));
    return r;
}
#endif

#define SC_IFO (-1.4426950408889634f)   // -log2(e)
#define SC_G   ( 2.8853900817779268f)   // +2*log2(e)

__device__ __forceinline__ unsigned short f32_to_bf16_rne(float f) {
    unsigned int u = __builtin_bit_cast(unsigned int, f);
    unsigned int r = u + 0x7fffu + ((u >> 16) & 1u);
    return (unsigned short)(r >> 16);
}
__device__ __forceinline__ bf16_t bits_to_bf16(unsigned short u) {
    return __builtin_bit_cast(bf16_t, u);
}
// single-term weight frag with per-row scale folded in (RNE)
__device__ __forceinline__ void build_frag_scaled(const float* __restrict__ p, float sc,
                                                  bf16x8& w) {
    const float4 a = *(const float4*)p;
    const float4 b = *(const float4*)(p + 4);
    float v[8] = {a.x, a.y, a.z, a.w, b.x, b.y, b.z, b.w};
#pragma unroll
    for (int jj = 0; jj < 8; ++jj)
        w[jj] = bits_to_bf16(f32_to_bf16_rne(v[jj] * sc));
}

__device__ __forceinline__ f32x2 exp2v(f32x2 v) {
    f32x2 r; r[0] = EXP2F(v[0]); r[1] = EXP2F(v[1]); return r;
}
__device__ __forceinline__ f32x2 rcpv(f32x2 v) {
    f32x2 r; r[0] = RCPF(v[0]); r[1] = RCPF(v[1]); return r;
}
// Two cells on PRE-SCALED gates (is,fs,os scaled -log2e; gs scaled +2log2e).
__device__ __forceinline__ f32x2 cell2(const f32x4 a0, const f32x4 a1, f32x2* c) {
    f32x2 is = {a0[0], a1[0]}, fs = {a0[1], a1[1]};
    f32x2 gs = {a0[2], a1[2]}, os = {a0[3], a1[3]};
    const f32x2 pf = exp2v(fs);
    const f32x2 fg = rcpv(1.0f + pf);
    const f32x2 pi = exp2v(is);
    const f32x2 e2 = exp2v(gs);
    const f32x2 z  = (e2 - 1.0f) * rcpv((1.0f + pi) * (1.0f + e2));
    *c = fg * (*c) + z;
    const f32x2 po  = exp2v(os);
    const f32x2 e2c = exp2v((*c) * SC_G);
    return (e2c - 1.0f) * rcpv((1.0f + po) * (1.0f + e2c));
}

__device__ __forceinline__ int imin2(int a, int b) { return a < b ? a : b; }
__device__ __forceinline__ int min4of(const int* f) {
    const int4 v = *(const int4*)f;
    return imin2(imin2(v.x, v.y), imin2(v.z, v.w));
}
__device__ __forceinline__ int min8of(const int* f) {
    const int4 a = *(const int4*)f;
    const int4 b = *(const int4*)(f + 4);
    return imin2(imin2(imin2(a.x, a.y), imin2(a.z, a.w)),
                 imin2(imin2(b.x, b.y), imin2(b.z, b.w)));
}

__global__ __launch_bounds__(768, 3)
void lstm_1t_kernel(const float* __restrict__ x,
                    const float* __restrict__ Wih0, const float* __restrict__ Whh0,
                    const float* __restrict__ bih0, const float* __restrict__ bhh0,
                    const float* __restrict__ Wih1, const float* __restrict__ Whh1,
                    const float* __restrict__ bih1, const float* __restrict__ bhh1,
                    const float* __restrict__ Wfc,  const float* __restrict__ bfc,
                    float* __restrict__ out)
{
    __shared__ float xbuf[NB][XP];                   // 33 KB
    __shared__ unsigned short h0r[8][NB][64];        // 16 KB ring, slot t&7
    __shared__ unsigned short h1r[2][NB][64];        // 4 KB ring, slot t&1
    __shared__ float h1fin[HH][NB + 1];              // 4.25 KB
    __shared__ __align__(16) int f0[4];              // L0 wave progress flags
    __shared__ __align__(16) int f1[8];              // L1 wave progress flags

    const int tid  = threadIdx.x;
    const int wv   = tid >> 6;       // 0..11: 0-3 L0 waves, 4-11 L1 waves
    const int lane = tid & 63;
    const int m    = lane & 15;      // batch col (B/C frag) & A-frag row-in-tile
    const int q    = lane >> 4;      // C-frag unit_local; A/B k-quad
    const int m7   = m & 7;
    const int b0   = blockIdx.x * NB;
    const bool isL0 = (wv < 4);

    // ---- stage x (coalesced float4) ----
    for (int i = tid; i < NB * TT / 4; i += 768) {
        const int b  = i >> 7;
        const int t4 = i & 127;
        *(float4*)&xbuf[b][t4 * 4] = *(const float4*)&x[(size_t)(b0 + b) * TT + t4 * 4];
    }
    // ---- zero rings (h(-1) served by zeroed slots) + flags ----
    for (int i = tid; i < 8 * NB * 64; i += 768) (&h0r[0][0][0])[i] = 0;
    for (int i = tid; i < 2 * NB * 64; i += 768) (&h1r[0][0][0])[i] = 0;
    if (tid < 4) f0[tid] = -1;
    else if (tid < 12) f1[tid - 4] = -1;

    // ---- per-lane read offsets (shorts within one slot = 1024) ----
    int roff[2];
#pragma unroll
    for (int kt = 0; kt < 2; ++kt)
        roff[kt] = m * 64 + (((4 * kt + q) ^ m7) * 8);

    const int gate_m = m & 3;
    const float scA  = (gate_m == 2) ? SC_G : SC_IFO;
    unsigned short* const H0 = &h0r[0][0][0];
    unsigned short* const H1 = &h1r[0][0][0];

    __syncthreads();     // the ONLY barrier before the epilogue

    if (isL0) {
        // ===== L0 waves: units [16w,16w+16), 4 unit-major tiles, 8 MFMA =====
        const int w = wv;
        bf16x8 Ah[4][2];                    // [tau][kt] of Whh0 (single-term)
        f32x4 bb0s[4], wx0s[4];
        int woff[4];
#pragma unroll
        for (int tau = 0; tau < 4; ++tau) {
            const int rowA = 64 * gate_m + 16 * w + 4 * tau + (m >> 2);
#pragma unroll
            for (int kt = 0; kt < 2; ++kt)
                build_frag_scaled(&Whh0[rowA * HH + kt * 32 + q * 8], scA, Ah[tau][kt]);
#pragma unroll
            for (int r = 0; r < 4; ++r) {
                const int row = 64 * r + 16 * w + 4 * tau + q;
                const float sc = (r == 2) ? SC_G : SC_IFO;
                bb0s[tau][r] = (bih0[row] + bhh0[row]) * sc;
                wx0s[tau][r] = Wih0[row] * sc;
            }
            const int u = 16 * w + 4 * tau + q;
            woff[tau] = m * 64 + (((u >> 3) ^ m7) * 8) + (u & 7);
        }

        f32x2 cA = {0.f, 0.f}, cB = {0.f, 0.f};

#pragma unroll 1
        for (int t = 0; t < TT; ++t) {
            // ---- wait for h0(t-1) complete (all 4 L0 waves) ----
            while (min4of(f0) < t - 1) {
                asm volatile("" ::: "memory");
                __builtin_amdgcn_s_sleep(1);
            }
            asm volatile("" ::: "memory");

            const int rs = ((t - 1) & 7) * (NB * 64);
            bf16x8 h0[2];
            h0[0] = *(const bf16x8*)(H0 + rs + roff[0]);
            h0[1] = *(const bf16x8*)(H0 + rs + roff[1]);
            const float xv = xbuf[m][t];

            f32x4 a[4];
#pragma unroll
            for (int tau = 0; tau < 4; ++tau) {
                f32x4 p;
#pragma unroll
                for (int r = 0; r < 4; ++r)
                    p[r] = __builtin_fmaf(xv, wx0s[tau][r], bb0s[tau][r]);
                f32x4 z = {0.f, 0.f, 0.f, 0.f};
                p = MFMA(Ah[tau][0], h0[0], p);
                z = MFMA(Ah[tau][1], h0[1], z);
                a[tau] = p + z;
            }

            // ---- back-pressure: slot t&7 (h0(t-8)) fully consumed by L1 ----
            while (min8of(f1) < t - 8) {
                asm volatile("" ::: "memory");
                __builtin_amdgcn_s_sleep(1);
            }
            asm volatile("" ::: "memory");

            const f32x2 hv0 = cell2(a[0], a[1], &cA);
            const f32x2 hv1 = cell2(a[2], a[3], &cB);

            const int ws = (t & 7) * (NB * 64);
            H0[ws + woff[0]] = f32_to_bf16_rne(hv0[0]);
            H0[ws + woff[1]] = f32_to_bf16_rne(hv0[1]);
            H0[ws + woff[2]] = f32_to_bf16_rne(hv1[0]);
            H0[ws + woff[3]] = f32_to_bf16_rne(hv1[1]);

            asm volatile("s_waitcnt lgkmcnt(0)" ::: "memory");
            if (lane == 0) *(volatile int*)&f0[w] = t;
        }
    } else {
        // ===== L1 waves: units [8u,8u+8), 2 tiles, 8 MFMA =====
        const int uW = wv - 4;
        bf16x8 Ah[2][4];     // [tau][kt]: kt0-1 Wih1 (eats h0), kt2-3 Whh1 (eats h1)
        f32x4 bb1s[2];
        int woff[2], uu[2];
#pragma unroll
        for (int tau = 0; tau < 2; ++tau) {
            const int rowA = 64 * gate_m + 8 * uW + 4 * tau + (m >> 2);
#pragma unroll
            for (int kt = 0; kt < 2; ++kt)
                build_frag_scaled(&Wih1[rowA * HH + kt * 32 + q * 8], scA, Ah[tau][kt]);
#pragma unroll
            for (int kt = 0; kt < 2; ++kt)
                build_frag_scaled(&Whh1[rowA * HH + kt * 32 + q * 8], scA, Ah[tau][2 + kt]);
#pragma unroll
            for (int r = 0; r < 4; ++r) {
                const int row = 64 * r + 8 * uW + 4 * tau + q;
                const float sc = (r == 2) ? SC_G : SC_IFO;
                bb1s[tau][r] = (bih1[row] + bhh1[row]) * sc;
            }
            const int u = 8 * uW + 4 * tau + q;
            uu[tau]   = u;
            woff[tau] = m * 64 + (((u >> 3) ^ m7) * 8) + (u & 7);
        }

        f32x2 c1 = {0.f, 0.f};

#pragma unroll 1
        for (int t = 0; t < TT; ++t) {
            // ---- wait for h0(t) (all 4 L0 waves) ----
            while (min4of(f0) < t) {
                asm volatile("" ::: "memory");
                __builtin_amdgcn_s_sleep(1);
            }
            asm volatile("" ::: "memory");
            const int rs0 = (t & 7) * (NB * 64);
            bf16x8 h0[2];
            h0[0] = *(const bf16x8*)(H0 + rs0 + roff[0]);
            h0[1] = *(const bf16x8*)(H0 + rs0 + roff[1]);

            // ---- wait for h1(t-1) (all 8 L1 waves) ----
            while (min8of(f1) < t - 1) {
                asm volatile("" ::: "memory");
                __builtin_amdgcn_s_sleep(1);
            }
            asm volatile("" ::: "memory");
            const int rs1 = ((t - 1) & 1) * (NB * 64);
            bf16x8 h1[2];
            h1[0] = *(const bf16x8*)(H1 + rs1 + roff[0]);
            h1[1] = *(const bf16x8*)(H1 + rs1 + roff[1]);

            f32x4 a[2];
#pragma unroll
            for (int tau = 0; tau < 2; ++tau) {
                f32x4 p = bb1s[tau];
                f32x4 s = {0.f, 0.f, 0.f, 0.f};
                p = MFMA(Ah[tau][0], h0[0], p);        // Wih1 . h0(t)
                p = MFMA(Ah[tau][1], h0[1], p);
                s = MFMA(Ah[tau][2], h1[0], s);        // Whh1 . h1(t-1)
                s = MFMA(Ah[tau][3], h1[1], s);
                a[tau] = p + s;
            }

            const f32x2 hv = cell2(a[0], a[1], &c1);
            if (t == TT - 1) {                  // exact fp32 h1(T-1) for FC
                h1fin[uu[0]][m] = hv[0];
                h1fin[uu[1]][m] = hv[1];
            }
            const int ws = (t & 1) * (NB * 64);
            H1[ws + woff[0]] = f32_to_bf16_rne(hv[0]);
            H1[ws + woff[1]] = f32_to_bf16_rne(hv[1]);

            asm volatile("s_waitcnt lgkmcnt(0)" ::: "memory");
            if (lane == 0) *(volatile int*)&f1[uW] = t;
        }
    }

    __syncthreads();

    // ---- FC epilogue: out[b] = h1(T-1)[b] . Wfc + bfc ----
    if (tid < NB) {
        float sacc = bfc[0];
#pragma unroll
        for (int u = 0; u < HH; ++u) sacc = fmaf(h1fin[u][tid], Wfc[u], sacc);
        out[b0 + tid] = sacc;
    }
}

extern "C" void kernel_launch(void* const* d_in, const int* in_sizes, int n_in,
                              void* d_out, int out_size, void* d_ws, size_t ws_size,
                              hipStream_t stream) {
    const float* x    = (const float*)d_in[0];
    const float* Wih0 = (const float*)d_in[1];
    const float* Whh0 = (const float*)d_in[2];
    const float* bih0 = (const float*)d_in[3];
    const float* bhh0 = (const float*)d_in[4];
    const float* Wih1 = (const float*)d_in[5];
    const float* Whh1 = (const float*)d_in[6];
    const float* bih1 = (const float*)d_in[7];
    const float* bhh1 = (const float*)d_in[8];
    const float* Wfc  = (const float*)d_in[9];
    const float* bfc  = (const float*)d_in[10];

    lstm_1t_kernel<<<dim3(4096 / NB), dim3(768), 0, stream>>>(
        x, Wih0, Whh0, bih0, bhh0, Wih1, Whh1, bih1, bhh1, Wfc, bfc, (float*)d_out);
}